// Round 7
// baseline (151.814 us; speedup 1.0000x reference)
//
#include <hip/hip_runtime.h>

#define NN 50000
#define EE 1600000
#define INF 128
#define OUTF 64
#define NH 2
#define ALPHA 0.2f

#define RNG 16            // node ranges
#define NPR (NN / RNG)    // 3125 nodes/range -> 25 KB bins
#define NBB 250           // bucket blocks (6400 edges each)
#define EPB (EE / NBB)    // 6400
#define BCAP 640          // segment capacity (mean 400, sigma ~19 -> +12 sigma)
#define NBNODE 196        // GEMM blocks (256 rows each)
#define HCH 25            // hist chunk blocks
#define SPB (NBB / HCH)   // 10 segments per hist block

typedef __attribute__((ext_vector_type(8))) short s16x8;
typedef __attribute__((ext_vector_type(4))) float f32x4;

__device__ __forceinline__ unsigned short bf16_rne(float f) {
    union { float f; unsigned u; } v; v.f = f;
    unsigned r = v.u + 0x7FFFu + ((v.u >> 16) & 1u);
    return (unsigned short)(r >> 16);
}
__device__ __forceinline__ float bf16_val(unsigned short h) {
    union { unsigned u; float f; } v; v.u = ((unsigned)h) << 16;
    return v.f;
}
__device__ __forceinline__ void split8(const float4 a, const float4 b,
                                       s16x8& hi, s16x8& lo) {
    const float p[8] = {a.x, a.y, a.z, a.w, b.x, b.y, b.z, b.w};
    #pragma unroll
    for (int j = 0; j < 8; ++j) {
        const unsigned short h = bf16_rne(p[j]);
        hi[j] = (short)h;
        lo[j] = (short)bf16_rne(p[j] - bf16_val(h));
    }
}

// ws layout (floats):
//   si      [0       , 100000)
//   sj      [100000  , 200000)
//   Z       [200000  , 200002)
//   counts  [200016  , 204016)   4000 ints (r*250 + bid)
//   buckets [204032  , 2764032)  16*250*640 packed uints
//   partial [2764032 , 5264032)  25 * 100000 floats

// Fused single entry kernel:
//   blocks [0,NBB)           : edge bucketing (counting sort by dst range) + Z init
//   blocks [NBB, NBB+NBNODE) : 256-row split-bf16 MFMA GEMM; W converted/swizzled
//                              into LDS in-block; u=W.a score tile in-block.
__global__ __launch_bounds__(512)
void gat_node(const float* __restrict__ x, const float* __restrict__ Wg,
              const float* __restrict__ av, const int* __restrict__ ei,
              float* __restrict__ out, float* __restrict__ si,
              float* __restrict__ sj, unsigned* __restrict__ buckets,
              int* __restrict__ counts, float* __restrict__ Z)
{
    __shared__ unsigned short WsL[36864];   // 72 KB: 9 B-tiles hi | 9 B-tiles lo
    __shared__ int cnt[16];
    const int tid = threadIdx.x;

    if (blockIdx.x < NBB) {               // ---- bucket path ----
        const int bid = blockIdx.x;
        if (bid == 0 && tid < 2) Z[tid] = 0.0f;
        if (tid < 16) cnt[tid] = 0;
        __syncthreads();
        const int e0 = bid * EPB;
        for (int i = tid; i < EPB / 4; i += 512) {
            const int4 s4 = *(const int4*)&ei[e0 + 4 * i];
            const int4 d4 = *(const int4*)&ei[EE + e0 + 4 * i];
            const int ss[4] = {s4.x, s4.y, s4.z, s4.w};
            const int dd[4] = {d4.x, d4.y, d4.z, d4.w};
            #pragma unroll
            for (int k = 0; k < 4; ++k) {
                const int r = dd[k] / NPR;
                const int rel = dd[k] - r * NPR;
                const int pos = atomicAdd(&cnt[r], 1);
                if (pos < BCAP)
                    buckets[(size_t)(r * NBB + bid) * BCAP + pos] =
                        (unsigned)ss[k] | ((unsigned)rel << 16);
            }
        }
        __syncthreads();
        if (tid < 16) counts[tid * NBB + bid] = min(cnt[tid], BCAP);
        return;
    }

    // ---- node GEMM path ----
    const int bx = blockIdx.x - NBB;
    const int lane = tid & 63;
    const int wv = tid >> 6;              // 8 waves
    const int lm = lane & 15;
    const int quad = lane >> 4;

    // stage: convert+swizzle W -> LDS B-fragments (tiles 0..7, hi|lo)
    for (int idx = tid; idx < 16384; idx += 512) {
        const int h = idx >> 13;          // W flat = h*8192 + k*64 + o
        const int k = (idx >> 6) & 127;
        const int o = idx & 63;
        const float w = Wg[idx];
        const unsigned short hi = bf16_rne(w);
        const unsigned short lo = bf16_rne(w - bf16_val(hi));
        const int n  = h * 64 + o;        // fused col (head-major)
        const int nt = n >> 4;
        const int ks = k >> 5;
        const int kk = k & 31;
        const int ln = (kk >> 3) * 16 + (n & 15);
        const int pos = ((nt * 4 + ks) * 64 + ln) * 8 + (kk & 7);
        WsL[pos] = hi;
        WsL[18432 + pos] = lo;
    }
    for (int i = tid; i < 2048; i += 512) {   // zero u-tile (tile 8)
        WsL[16384 + i] = 0;
        WsL[18432 + 16384 + i] = 0;
    }
    __syncthreads();
    if (tid < 128) {                      // u = W.a -> tile 8 (cols 0..3)
        const int k = tid;
        float u0 = 0.f, u1 = 0.f, u2 = 0.f, u3 = 0.f;
        #pragma unroll 4
        for (int o = 0; o < 64; o += 4) {
            const float4 w0 = *(const float4*)&Wg[k * 64 + o];
            const float4 w1 = *(const float4*)&Wg[8192 + k * 64 + o];
            const float4 ai0 = *(const float4*)&av[o];
            const float4 aj0 = *(const float4*)&av[64 + o];
            const float4 ai1 = *(const float4*)&av[128 + o];
            const float4 aj1 = *(const float4*)&av[192 + o];
            u0 += w0.x*ai0.x + w0.y*ai0.y + w0.z*ai0.z + w0.w*ai0.w;
            u1 += w0.x*aj0.x + w0.y*aj0.y + w0.z*aj0.z + w0.w*aj0.w;
            u2 += w1.x*ai1.x + w1.y*ai1.y + w1.z*ai1.z + w1.w*ai1.w;
            u3 += w1.x*aj1.x + w1.y*aj1.y + w1.z*aj1.z + w1.w*aj1.w;
        }
        const float uu[4] = {u0, u1, u2, u3};
        const int ks = k >> 5;
        const int kk = k & 31;
        #pragma unroll
        for (int n = 0; n < 4; ++n) {
            const int ln = (kk >> 3) * 16 + n;
            const int pos = ((32 + ks) * 64 + ln) * 8 + (kk & 7);
            const unsigned short hi = bf16_rne(uu[n]);
            WsL[pos] = hi;
            WsL[18432 + pos] = bf16_rne(uu[n] - bf16_val(hi));
        }
    }

    const int rowA0 = bx * 256 + wv * 32 + lm;   // m-tile 0
    const int rowA1 = rowA0 + 16;                // m-tile 1
    const int rc0 = rowA0 < NN ? rowA0 : NN - 1;
    const int rc1 = rowA1 < NN ? rowA1 : NN - 1;
    const float* xp0 = x + (size_t)rc0 * INF + quad * 8;
    const float* xp1 = x + (size_t)rc1 * INF + quad * 8;

    f32x4 acc[2][9];
    #pragma unroll
    for (int mi = 0; mi < 2; ++mi)
        #pragma unroll
        for (int nt = 0; nt < 9; ++nt) acc[mi][nt] = (f32x4)0.0f;

    __syncthreads();

    #pragma unroll
    for (int ks = 0; ks < 4; ++ks) {
        s16x8 ah0, al0, ah1, al1;
        {
            const float4 u0 = *(const float4*)(xp0 + ks * 32);
            const float4 v0 = *(const float4*)(xp0 + ks * 32 + 4);
            split8(u0, v0, ah0, al0);
            const float4 u1 = *(const float4*)(xp1 + ks * 32);
            const float4 v1 = *(const float4*)(xp1 + ks * 32 + 4);
            split8(u1, v1, ah1, al1);
        }
        #pragma unroll
        for (int nt = 0; nt < 9; ++nt) {
            const s16x8 bh = *(const s16x8*)&WsL[((nt * 4 + ks) * 64 + lane) * 8];
            const s16x8 bl = *(const s16x8*)&WsL[18432 + ((nt * 4 + ks) * 64 + lane) * 8];
            acc[0][nt] = __builtin_amdgcn_mfma_f32_16x16x32_bf16(ah0, bh, acc[0][nt], 0, 0, 0);
            acc[0][nt] = __builtin_amdgcn_mfma_f32_16x16x32_bf16(ah0, bl, acc[0][nt], 0, 0, 0);
            acc[0][nt] = __builtin_amdgcn_mfma_f32_16x16x32_bf16(al0, bh, acc[0][nt], 0, 0, 0);
            acc[1][nt] = __builtin_amdgcn_mfma_f32_16x16x32_bf16(ah1, bh, acc[1][nt], 0, 0, 0);
            acc[1][nt] = __builtin_amdgcn_mfma_f32_16x16x32_bf16(ah1, bl, acc[1][nt], 0, 0, 0);
            acc[1][nt] = __builtin_amdgcn_mfma_f32_16x16x32_bf16(al1, bh, acc[1][nt], 0, 0, 0);
        }
    }

    // epilogue: C/D layout col = lane&15, row = quad*4 + reg
    #pragma unroll
    for (int mi = 0; mi < 2; ++mi) {
        const int rowb = bx * 256 + wv * 32 + mi * 16 + quad * 4;
        #pragma unroll
        for (int r = 0; r < 4; ++r) {
            const int rr = rowb + r;
            if (rr < NN) {
                // u tile: col0=s_i h0, col1=s_j h0, col2=s_i h1, col3=s_j h1
                const float sv = acc[mi][8][r];
                if (lm == 0)      si[2 * rr] = sv;
                else if (lm == 1) sj[2 * rr] = sv;
                else if (lm == 2) si[2 * rr + 1] = sv;
                else if (lm == 3) sj[2 * rr + 1] = sv;
                float* orow = out + (size_t)rr * (NH * OUTF) + lm;
                #pragma unroll
                for (int nt = 0; nt < 8; ++nt) orow[nt * 16] = acc[mi][nt][r];
            }
        }
    }
}

// grid (HCH, RNG): block (c,r) drains bucket segments b = c*SPB .. +SPB-1 of
// range r into LDS bins; flushes partial[c] + Z atomics.
__global__ __launch_bounds__(512)
void gat_hist(const unsigned* __restrict__ buckets, const int* __restrict__ counts,
              const float* __restrict__ si, const float* __restrict__ sj,
              float* __restrict__ partial, float* __restrict__ Z)
{
    __shared__ float bins[NPR * 2];   // 25 KB
    __shared__ float zr0[8], zr1[8];
    const int c = blockIdx.x;
    const int r = blockIdx.y;
    const int nlo = r * NPR;

    for (int i = threadIdx.x; i < NPR; i += 512)
        ((float2*)bins)[i] = make_float2(0.f, 0.f);
    __syncthreads();

    float z0 = 0.f, z1 = 0.f;
    #pragma unroll
    for (int bb = 0; bb < SPB; ++bb) {
        const int b = c * SPB + bb;
        const int n = counts[r * NBB + b];
        const uint4* seg4 = (const uint4*)(buckets + (size_t)(r * NBB + b) * BCAP);
        const int n4 = (n + 3) >> 2;
        for (int i = threadIdx.x; i < n4; i += 512) {
            const uint4 pk4 = seg4[i];
            const unsigned pks[4] = {pk4.x, pk4.y, pk4.z, pk4.w};
            #pragma unroll
            for (int j = 0; j < 4; ++j) {
                if (4 * i + j < n) {
                    const unsigned pk = pks[j];
                    const int s = (int)(pk & 0xFFFFu);
                    const int rel = (int)(pk >> 16);
                    const float2 vi = *(const float2*)&si[2 * s];
                    const float2 vj = *(const float2*)&sj[2 * (nlo + rel)];
                    float a0 = vi.x + vj.x; a0 = a0 > 0.f ? a0 : ALPHA * a0;
                    float a1 = vi.y + vj.y; a1 = a1 > 0.f ? a1 : ALPHA * a1;
                    const float w0 = expf(a0);
                    const float w1 = expf(a1);
                    atomicAdd(&bins[2 * rel], w0);
                    atomicAdd(&bins[2 * rel + 1], w1);
                    z0 += w0; z1 += w1;
                }
            }
        }
    }

    #pragma unroll
    for (int m = 1; m < 64; m <<= 1) {
        z0 += __shfl_xor(z0, m, 64);
        z1 += __shfl_xor(z1, m, 64);
    }
    const int wv = threadIdx.x >> 6;
    if ((threadIdx.x & 63) == 0) { zr0[wv] = z0; zr1[wv] = z1; }
    __syncthreads();
    if (threadIdx.x == 0) {
        float t0 = 0.f, t1 = 0.f;
        #pragma unroll
        for (int i = 0; i < 8; ++i) { t0 += zr0[i]; t1 += zr1[i]; }
        atomicAdd(&Z[0], t0);
        atomicAdd(&Z[1], t1);
    }

    float2* P = (float2*)(partial + (size_t)c * 100000 + nlo * 2);
    for (int i = threadIdx.x; i < NPR; i += 512)
        P[i] = ((const float2*)bins)[i];
}

// Fused sum+final: reduce partials for 128 nodes, then scale their out rows.
__global__ __launch_bounds__(256)
void gat_scale(float* __restrict__ out, const float* __restrict__ partial,
               const float* __restrict__ Z)
{
    __shared__ float sc[256];
    const int tid = threadIdx.x;
    const int n0 = blockIdx.x * 128;
    const float rz0 = 1.0f / Z[0];
    const float rz1 = 1.0f / Z[1];

    const int nvals = min(256, 100000 - n0 * 2);
    if (tid < nvals) {
        float ssum = 0.f;
        #pragma unroll 5
        for (int c = 0; c < HCH; ++c)
            ssum += partial[(size_t)c * 100000 + n0 * 2 + tid];
        sc[tid] = ssum * ((tid & 1) ? rz1 : rz0);
    }
    __syncthreads();

    float4* ob = (float4*)(out + (size_t)n0 * 128);
    const int lim4 = min(128, NN - n0) * 32;
    for (int i = tid; i < lim4; i += 256) {
        const int row = i >> 5;
        const int c4 = i & 31;               // head = c4>>4
        const float s = sc[row * 2 + (c4 >> 4)];
        float4 v = ob[i];
        v.x *= s; v.y *= s; v.z *= s; v.w *= s;
        ob[i] = v;
    }
}

extern "C" void kernel_launch(void* const* d_in, const int* in_sizes, int n_in,
                              void* d_out, int out_size, void* d_ws, size_t ws_size,
                              hipStream_t stream)
{
    const float* x = (const float*)d_in[0];
    const float* W = (const float*)d_in[1];
    const float* a = (const float*)d_in[2];
    const int* ei = (const int*)d_in[3];
    float* out = (float*)d_out;
    float* ws = (float*)d_ws;

    float* si = ws;
    float* sj = ws + 100000;
    float* Z = ws + 200000;
    int* counts = (int*)(ws + 200016);
    unsigned* buckets = (unsigned*)(ws + 204032);
    float* partial = ws + 2764032;

    gat_node<<<dim3(NBB + NBNODE), dim3(512), 0, stream>>>(x, W, a, ei, out, si, sj,
                                                           buckets, counts, Z);

    gat_hist<<<dim3(HCH, RNG), dim3(512), 0, stream>>>(buckets, counts, si, sj,
                                                       partial, Z);

    gat_scale<<<dim3((NN + 127) / 128), dim3(256), 0, stream>>>(out, partial, Z);
}

// Round 8
// 145.137 us; speedup vs baseline: 1.0460x; 1.0460x over previous
//
#include <hip/hip_runtime.h>

#define NN 50000
#define EE 1600000
#define INF 128
#define OUTF 64
#define NH 2
#define ALPHA 0.2f

#define RNG 16            // node ranges
#define NPR (NN / RNG)    // 3125 nodes/range -> 25 KB bins
#define NBB 64            // bucket blocks (25000 edges each)
#define EPB (EE / NBB)    // 25000
#define BCAP 2048         // segment capacity (mean 1562, sigma ~38 -> +12 sigma)
#define NSPREP 391        // sprep blocks (128 rows each)
#define NWPREP 64         // wprep blocks
#define NBNODE 391        // GEMM blocks (128 rows each)
#define HCH 16            // hist chunk blocks
#define SPB (NBB / HCH)   // 4 segments per hist block

typedef __attribute__((ext_vector_type(8))) short s16x8;
typedef __attribute__((ext_vector_type(4))) float f32x4;

__device__ __forceinline__ unsigned short bf16_rne(float f) {
    union { float f; unsigned u; } v; v.f = f;
    unsigned r = v.u + 0x7FFFu + ((v.u >> 16) & 1u);
    return (unsigned short)(r >> 16);
}
__device__ __forceinline__ float bf16_val(unsigned short h) {
    union { unsigned u; float f; } v; v.u = ((unsigned)h) << 16;
    return v.f;
}
__device__ __forceinline__ void split8(const float4 a, const float4 b,
                                       s16x8& hi, s16x8& lo) {
    const float p[8] = {a.x, a.y, a.z, a.w, b.x, b.y, b.z, b.w};
    #pragma unroll
    for (int j = 0; j < 8; ++j) {
        const unsigned short h = bf16_rne(p[j]);
        hi[j] = (short)h;
        lo[j] = (short)bf16_rne(p[j] - bf16_val(h));
    }
}

// ws layout (floats):
//   si      [0       , 100000)
//   sj      [100000  , 200000)
//   Z       [200000  , 200002)
//   counts  [200016  , 201040)   16*64 ints
//   Wf      [201056  , 217440)   32768 ushorts: 8 B-tiles hi | 8 lo
//   buckets [217472  , 2314624)  16*64*2048 packed uints
//   partial [2314624 , 3914624)  16 * 100000 floats

// K1: blocks [0,NSPREP)              : s_i/s_j = x.(W.a) fp32 GEMV
//     blocks [NSPREP, NSPREP+NBB)    : edge bucketing by dst range
//     blocks [NSPREP+NBB, +NWPREP)   : W -> split-bf16 B-fragments + Z init
__global__ __launch_bounds__(256)
void gat_prep(const float* __restrict__ x, const float* __restrict__ Wg,
              const float* __restrict__ av, const int* __restrict__ ei,
              float* __restrict__ si, float* __restrict__ sj,
              unsigned short* __restrict__ Wf, unsigned* __restrict__ buckets,
              int* __restrict__ counts, float* __restrict__ Z)
{
    __shared__ float4 u4[128];   // {ui_h0, uj_h0, ui_h1, uj_h1} per k
    __shared__ int cnt[16];
    const int tid = threadIdx.x;

    if (blockIdx.x >= NSPREP + NBB) {     // ---- wprep path ----
        const int idx = (blockIdx.x - (NSPREP + NBB)) * 256 + tid;  // 0..16383
        if (idx < 2) Z[idx] = 0.0f;
        const int h = idx >> 13;          // W flat = h*8192 + k*64 + o
        const int k = (idx >> 6) & 127;
        const int o = idx & 63;
        const float w = Wg[idx];
        const unsigned short hi = bf16_rne(w);
        const unsigned short lo = bf16_rne(w - bf16_val(hi));
        const int n  = h * 64 + o;        // fused col (head-major)
        const int nt = n >> 4;
        const int ks = k >> 5;
        const int kk = k & 31;
        const int ln = (kk >> 3) * 16 + (n & 15);
        const int pos = ((nt * 4 + ks) * 64 + ln) * 8 + (kk & 7);
        Wf[pos] = hi;
        Wf[16384 + pos] = lo;
        return;
    }

    if (blockIdx.x >= NSPREP) {           // ---- bucket path ----
        const int bid = blockIdx.x - NSPREP;
        if (tid < 16) cnt[tid] = 0;
        __syncthreads();
        const int e0 = bid * EPB;
        for (int i = tid; i < EPB / 4; i += 256) {
            const int4 s4 = *(const int4*)&ei[e0 + 4 * i];
            const int4 d4 = *(const int4*)&ei[EE + e0 + 4 * i];
            const int ss[4] = {s4.x, s4.y, s4.z, s4.w};
            const int dd[4] = {d4.x, d4.y, d4.z, d4.w};
            #pragma unroll
            for (int k = 0; k < 4; ++k) {
                const int r = dd[k] / NPR;
                const int rel = dd[k] - r * NPR;
                const int pos = atomicAdd(&cnt[r], 1);
                if (pos < BCAP)
                    buckets[(size_t)(r * NBB + bid) * BCAP + pos] =
                        (unsigned)ss[k] | ((unsigned)rel << 16);
            }
        }
        __syncthreads();
        if (tid < 16) counts[tid * NBB + bid] = min(cnt[tid], BCAP);
        return;
    }

    // ---- sprep path: scores via u = W.a (per-block, L2-hot) ----
    if (tid < 128) {
        const int k = tid;
        float u0 = 0.f, u1 = 0.f, u2 = 0.f, u3 = 0.f;
        #pragma unroll 4
        for (int o = 0; o < 64; o += 4) {
            const float4 w0 = *(const float4*)&Wg[k * 64 + o];
            const float4 w1 = *(const float4*)&Wg[8192 + k * 64 + o];
            const float4 ai0 = *(const float4*)&av[o];
            const float4 aj0 = *(const float4*)&av[64 + o];
            const float4 ai1 = *(const float4*)&av[128 + o];
            const float4 aj1 = *(const float4*)&av[192 + o];
            u0 += w0.x*ai0.x + w0.y*ai0.y + w0.z*ai0.z + w0.w*ai0.w;
            u1 += w0.x*aj0.x + w0.y*aj0.y + w0.z*aj0.z + w0.w*aj0.w;
            u2 += w1.x*ai1.x + w1.y*ai1.y + w1.z*ai1.z + w1.w*ai1.w;
            u3 += w1.x*aj1.x + w1.y*aj1.y + w1.z*aj1.z + w1.w*aj1.w;
        }
        u4[k] = make_float4(u0, u1, u2, u3);
    }
    __syncthreads();

    const int lane = tid & 63;
    const int wv = tid >> 6;
    const int lm = lane & 15;
    const int rsub = lane >> 4;           // 4 rows per wave

    #pragma unroll
    for (int p = 0; p < 8; ++p) {         // 128 rows/block
        const int row = blockIdx.x * 128 + p * 16 + wv * 4 + rsub;
        const int rc = row < NN ? row : NN - 1;
        const float4 xa = *(const float4*)(x + (size_t)rc * INF + lm * 8);
        const float4 xb = *(const float4*)(x + (size_t)rc * INF + lm * 8 + 4);
        float s0 = 0.f, s1 = 0.f, s2 = 0.f, s3 = 0.f;
        const float xv[8] = {xa.x, xa.y, xa.z, xa.w, xb.x, xb.y, xb.z, xb.w};
        #pragma unroll
        for (int j = 0; j < 8; ++j) {
            const float4 u = u4[lm * 8 + j];
            s0 = fmaf(xv[j], u.x, s0);
            s1 = fmaf(xv[j], u.y, s1);
            s2 = fmaf(xv[j], u.z, s2);
            s3 = fmaf(xv[j], u.w, s3);
        }
        #pragma unroll
        for (int m = 1; m < 16; m <<= 1) {
            s0 += __shfl_xor(s0, m, 64);
            s1 += __shfl_xor(s1, m, 64);
            s2 += __shfl_xor(s2, m, 64);
            s3 += __shfl_xor(s3, m, 64);
        }
        if (lm == 0 && row < NN) {
            *(float2*)&si[2 * row] = make_float2(s0, s2);
            *(float2*)&sj[2 * row] = make_float2(s1, s3);
        }
    }
}

// K2: grid (HCH, RNG): block (c,r) drains 4 bucket segments of range r into
// LDS bins; flushes partial[c] + Z atomics.
__global__ __launch_bounds__(512)
void gat_hist(const unsigned* __restrict__ buckets, const int* __restrict__ counts,
              const float* __restrict__ si, const float* __restrict__ sj,
              float* __restrict__ partial, float* __restrict__ Z)
{
    __shared__ float bins[NPR * 2];   // 25 KB
    __shared__ float zr0[8], zr1[8];
    const int c = blockIdx.x;
    const int r = blockIdx.y;
    const int nlo = r * NPR;

    for (int i = threadIdx.x; i < NPR; i += 512)
        ((float2*)bins)[i] = make_float2(0.f, 0.f);
    __syncthreads();

    float z0 = 0.f, z1 = 0.f;
    #pragma unroll
    for (int bb = 0; bb < SPB; ++bb) {
        const int b = c * SPB + bb;
        const int n = counts[r * NBB + b];
        const uint4* seg4 = (const uint4*)(buckets + (size_t)(r * NBB + b) * BCAP);
        const int n4 = (n + 3) >> 2;
        for (int i = threadIdx.x; i < n4; i += 512) {
            const uint4 pk4 = seg4[i];
            const unsigned pks[4] = {pk4.x, pk4.y, pk4.z, pk4.w};
            #pragma unroll
            for (int j = 0; j < 4; ++j) {
                if (4 * i + j < n) {
                    const unsigned pk = pks[j];
                    const int s = (int)(pk & 0xFFFFu);
                    const int rel = (int)(pk >> 16);
                    const float2 vi = *(const float2*)&si[2 * s];
                    const float2 vj = *(const float2*)&sj[2 * (nlo + rel)];
                    float a0 = vi.x + vj.x; a0 = a0 > 0.f ? a0 : ALPHA * a0;
                    float a1 = vi.y + vj.y; a1 = a1 > 0.f ? a1 : ALPHA * a1;
                    const float w0 = expf(a0);
                    const float w1 = expf(a1);
                    atomicAdd(&bins[2 * rel], w0);
                    atomicAdd(&bins[2 * rel + 1], w1);
                    z0 += w0; z1 += w1;
                }
            }
        }
    }

    #pragma unroll
    for (int m = 1; m < 64; m <<= 1) {
        z0 += __shfl_xor(z0, m, 64);
        z1 += __shfl_xor(z1, m, 64);
    }
    const int wv = threadIdx.x >> 6;
    if ((threadIdx.x & 63) == 0) { zr0[wv] = z0; zr1[wv] = z1; }
    __syncthreads();
    if (threadIdx.x == 0) {
        float t0 = 0.f, t1 = 0.f;
        #pragma unroll
        for (int i = 0; i < 8; ++i) { t0 += zr0[i]; t1 += zr1[i]; }
        atomicAdd(&Z[0], t0);
        atomicAdd(&Z[1], t1);
    }

    float2* P = (float2*)(partial + (size_t)c * 100000 + nlo * 2);
    for (int i = threadIdx.x; i < NPR; i += 512)
        P[i] = ((const float2*)bins)[i];
}

// K3: split-bf16 MFMA GEMM with LDS-staged B, fused attention scaling.
__global__ __launch_bounds__(256)
void gat_node(const float* __restrict__ x, const unsigned short* __restrict__ Wf,
              const float* __restrict__ partial, const float* __restrict__ Z,
              float* __restrict__ out)
{
    __shared__ unsigned short WsL[32768];   // 64 KB: 8 B-tiles hi | 8 lo
    const int tid = threadIdx.x;
    const int lane = tid & 63;
    const int wv = tid >> 6;
    const int lm = lane & 15;
    const int quad = lane >> 4;

    {   // stage B-fragments global -> LDS (plain copy)
        const float4* gsrc = (const float4*)Wf;   // 4096 float4
        float4* ldst = (float4*)WsL;
        #pragma unroll
        for (int i = 0; i < 16; ++i)
            ldst[i * 256 + tid] = gsrc[i * 256 + tid];
    }

    const float rz0 = 1.0f / Z[0];
    const float rz1 = 1.0f / Z[1];

    const int rowA0 = blockIdx.x * 128 + wv * 32 + lm;   // m-tile 0
    const int rowA1 = rowA0 + 16;                        // m-tile 1
    const int rc0 = rowA0 < NN ? rowA0 : NN - 1;
    const int rc1 = rowA1 < NN ? rowA1 : NN - 1;
    const float* xp0 = x + (size_t)rc0 * INF + quad * 8;
    const float* xp1 = x + (size_t)rc1 * INF + quad * 8;

    f32x4 acc[2][8];
    #pragma unroll
    for (int mi = 0; mi < 2; ++mi)
        #pragma unroll
        for (int nt = 0; nt < 8; ++nt) acc[mi][nt] = (f32x4)0.0f;

    __syncthreads();

    #pragma unroll
    for (int ks = 0; ks < 4; ++ks) {
        s16x8 ah0, al0, ah1, al1;
        {
            const float4 u0 = *(const float4*)(xp0 + ks * 32);
            const float4 v0 = *(const float4*)(xp0 + ks * 32 + 4);
            split8(u0, v0, ah0, al0);
            const float4 u1 = *(const float4*)(xp1 + ks * 32);
            const float4 v1 = *(const float4*)(xp1 + ks * 32 + 4);
            split8(u1, v1, ah1, al1);
        }
        #pragma unroll
        for (int nt = 0; nt < 8; ++nt) {
            const s16x8 bh = *(const s16x8*)&WsL[((nt * 4 + ks) * 64 + lane) * 8];
            const s16x8 bl = *(const s16x8*)&WsL[16384 + ((nt * 4 + ks) * 64 + lane) * 8];
            acc[0][nt] = __builtin_amdgcn_mfma_f32_16x16x32_bf16(ah0, bh, acc[0][nt], 0, 0, 0);
            acc[0][nt] = __builtin_amdgcn_mfma_f32_16x16x32_bf16(ah0, bl, acc[0][nt], 0, 0, 0);
            acc[0][nt] = __builtin_amdgcn_mfma_f32_16x16x32_bf16(al0, bh, acc[0][nt], 0, 0, 0);
            acc[1][nt] = __builtin_amdgcn_mfma_f32_16x16x32_bf16(ah1, bh, acc[1][nt], 0, 0, 0);
            acc[1][nt] = __builtin_amdgcn_mfma_f32_16x16x32_bf16(ah1, bl, acc[1][nt], 0, 0, 0);
            acc[1][nt] = __builtin_amdgcn_mfma_f32_16x16x32_bf16(al1, bh, acc[1][nt], 0, 0, 0);
        }
    }

    // epilogue: per row sum 16 partial chunks (lm lanes parallel) and scale.
    // C/D layout: col = lane&15, row = quad*4 + reg.
    #pragma unroll
    for (int mi = 0; mi < 2; ++mi) {
        const int rowb = blockIdx.x * 128 + wv * 32 + mi * 16 + quad * 4;
        #pragma unroll
        for (int r = 0; r < 4; ++r) {
            const int rr = rowb + r;
            const int rrc = rr < NN ? rr : NN - 1;
            float v0 = partial[(size_t)lm * 100000 + 2 * rrc];
            float v1 = partial[(size_t)lm * 100000 + 2 * rrc + 1];
            #pragma unroll
            for (int m = 1; m < 16; m <<= 1) {
                v0 += __shfl_xor(v0, m, 64);
                v1 += __shfl_xor(v1, m, 64);
            }
            const float sc0 = v0 * rz0;
            const float sc1 = v1 * rz1;
            if (rr < NN) {
                float* orow = out + (size_t)rr * (NH * OUTF) + lm;
                #pragma unroll
                for (int nt = 0; nt < 8; ++nt)
                    orow[nt * 16] = acc[mi][nt][r] * (nt < 4 ? sc0 : sc1);
            }
        }
    }
}

extern "C" void kernel_launch(void* const* d_in, const int* in_sizes, int n_in,
                              void* d_out, int out_size, void* d_ws, size_t ws_size,
                              hipStream_t stream)
{
    const float* x = (const float*)d_in[0];
    const float* W = (const float*)d_in[1];
    const float* a = (const float*)d_in[2];
    const int* ei = (const int*)d_in[3];
    float* out = (float*)d_out;
    float* ws = (float*)d_ws;

    float* si = ws;
    float* sj = ws + 100000;
    float* Z = ws + 200000;
    int* counts = (int*)(ws + 200016);
    unsigned short* Wf = (unsigned short*)(ws + 201056);
    unsigned* buckets = (unsigned*)(ws + 217472);
    float* partial = ws + 2314624;

    gat_prep<<<dim3(NSPREP + NBB + NWPREP), dim3(256), 0, stream>>>(
        x, W, a, ei, si, sj, Wf, buckets, counts, Z);

    gat_hist<<<dim3(HCH, RNG), dim3(512), 0, stream>>>(buckets, counts, si, sj,
                                                       partial, Z);

    gat_node<<<dim3(NBNODE), dim3(256), 0, stream>>>(x, Wf, partial, Z, out);
}